// Round 13
// baseline (294.928 us; speedup 1.0000x reference)
//
#include <hip/hip_runtime.h>
#include <hip/hip_bf16.h>

#define ALPHA 2.0f
#define BETA 50.0f
#define BASE 0.5f
#define MARGIN 0.1f

constexpr int NB = 8192;   // batch
constexpr int ND = 1024;   // dim
constexpr int BK = 64;     // K-tile
constexpr int NT = ND / BK; // 16 K-tiles

typedef __attribute__((ext_vector_type(8))) short bf16x8;
typedef __attribute__((ext_vector_type(4))) float f32x4;

#define GLOAD_LDS16(g, l) \
  __builtin_amdgcn_global_load_lds((const __attribute__((address_space(1))) void*)(g), \
                                   (__attribute__((address_space(3))) void*)(l), 16, 0, 0)
#define BAR()    __builtin_amdgcn_s_barrier()
#define WAITV(N) asm volatile("s_waitcnt vmcnt(" #N ")" ::: "memory")
#define SCHEDB() __builtin_amdgcn_sched_barrier(0)

static __device__ inline unsigned short f2bf(float x) {
  unsigned int u = __float_as_uint(x);
  unsigned int r = u + 0x7FFFu + ((u >> 16) & 1u);
  return (unsigned short)(r >> 16);
}

// --------------------------------------------------------------------------
// K1: row-normalize f1,f2 -> bf16; diag[i] = dot(f1n_i, f2n_i); zero sums.
__global__ __launch_bounds__(256) void norm_diag_kernel(
    const float* __restrict__ f1, const float* __restrict__ f2,
    unsigned short* __restrict__ f1n, unsigned short* __restrict__ f2n,
    float* __restrict__ diag, float* __restrict__ row_sum,
    float* __restrict__ col_sum)
{
  const int row = blockIdx.x;
  const int tid = threadIdx.x;
  const float4* r1 = (const float4*)(f1 + (size_t)row * ND);
  const float4* r2 = (const float4*)(f2 + (size_t)row * ND);
  float4 a = r1[tid];
  float4 b = r2[tid];
  float ss1 = a.x*a.x + a.y*a.y + a.z*a.z + a.w*a.w;
  float ss2 = b.x*b.x + b.y*b.y + b.z*b.z + b.w*b.w;
  float d12 = a.x*b.x + a.y*b.y + a.z*b.z + a.w*b.w;
  #pragma unroll
  for (int m = 1; m < 64; m <<= 1) {
    ss1 += __shfl_xor(ss1, m);
    ss2 += __shfl_xor(ss2, m);
    d12 += __shfl_xor(d12, m);
  }
  __shared__ float red[3][4];
  const int wid = tid >> 6, lane = tid & 63;
  if (lane == 0) { red[0][wid] = ss1; red[1][wid] = ss2; red[2][wid] = d12; }
  __syncthreads();
  ss1 = red[0][0] + red[0][1] + red[0][2] + red[0][3];
  ss2 = red[1][0] + red[1][1] + red[1][2] + red[1][3];
  d12 = red[2][0] + red[2][1] + red[2][2] + red[2][3];
  const float rn1 = rsqrtf(ss1);
  const float rn2 = rsqrtf(ss2);
  if (tid == 0) diag[row] = d12 * rn1 * rn2;
  if (tid == 1) row_sum[row] = 0.f;
  if (tid == 2) col_sum[row] = 0.f;
  ushort4 o1, o2;
  o1.x = f2bf(a.x * rn1); o1.y = f2bf(a.y * rn1);
  o1.z = f2bf(a.z * rn1); o1.w = f2bf(a.w * rn1);
  o2.x = f2bf(b.x * rn2); o2.y = f2bf(b.y * rn2);
  o2.z = f2bf(b.z * rn2); o2.w = f2bf(b.w * rn2);
  ((ushort4*)f1n)[(size_t)row * 256 + tid] = o1;
  ((ushort4*)f2n)[(size_t)row * 256 + tid] = o2;
}

// --------------------------------------------------------------------------
// K2: 256x256 tile, 8 waves, read-ahead pipelined phases.
//
// CORRECTNESS RULE (R10 post-mortem): vmcnt is PER-WAVE but staging is
// COOPERATIVE (each region written by all 8 waves). Any ds_read of a staged
// region must be preceded IN PROGRAM ORDER by {every wave: WAITV covering
// that region} + s_barrier. Pattern: STAGE; WAITV(4); BAR; SCHEDB; RD_next.
// The RD's consumer is 2-4 phases later, so the backend emits a partial
// lgkmcnt before the adjacent MFMA cluster -> read drain overlaps MFMA.
//
// Stage order: ...B0(t+1)[p3,t-1], A0(t+1)[p4,t-1], B1(t+1)[p1,t],
//   A1(t+1)[p2,t], B0(t+2)[p3,t], A0(t+2)[p4,t]...
// p3 WAITV(4)+BAR: all waves' B0,A0,B1(t+1) complete -> RD_B0(t+1) safe for
//   every wn band (wn=0,1 read B-lo=B0; wn=2,3 read B-hi=B1).
// p4 WAITV(4)+BAR: A1(t+1) complete -> RD_ALO(t+1) safe for wm=0 (A-lo=A0)
//   and wm=1 (A-hi=A1).
// Invariant at tile start: outstanding = {B0(t+1),A0(t+1)} = 4 loads/wave.
// WAR (stage >=1 barrier after its region's readers' consuming MFMA):
//   p1 stage B1(t+1)->S[NI].Bhi: last reader RD_B1@p1(t-1) consumed Q01@
//     p2(t-1) -> >=5 BARs. p2 stage A1(t+1)->S[NI].Ahi: RD_AHI@p2(t-1)
//     consumed Q10@p3(t-1) -> >=4 BARs. p3 stage B0(t+2)->S[BI].Blo: RD_B1@
//     p1(t) consumed Q01@p2(t) -> >=1 BAR. p4 stage A0(t+2)->S[BI].Alo:
//     RD_AHI@p2(t) consumed Q10@p3(t) -> >=1 BAR.
// Tail wrap (t=14,15): stages/reads hit valid LDS/global, land in dead regs.
__global__ __launch_bounds__(512, 2) void simloss_gemm_kernel(
    const unsigned short* __restrict__ f1n, const unsigned short* __restrict__ f2n,
    const float* __restrict__ diag,
    float* __restrict__ row_sum, float* __restrict__ col_sum)
{
  __shared__ unsigned short S[2][2][16384];  // [dbuf][A/B][256 x 64]
  __shared__ float drow[256];
  __shared__ float dcol[256];

  const int tid  = threadIdx.x;
  const int lane = tid & 63;
  const int wid  = tid >> 6;
  const int wm   = wid >> 2;   // 0..1 -> rows [wm*128, +128)
  const int wn   = wid & 3;    // 0..3 -> cols [wn*64, +64)

  // T1 bijective XCD swizzle (1024 blocks, 8 XCDs)
  const int bidl = blockIdx.y * gridDim.x + blockIdx.x;
  const int xcd  = bidl & 7;
  const int i128 = bidl >> 3;
  const int by   = xcd * 4 + (i128 & 3);
  const int bx   = i128 >> 2;
  const int brow = by * 256;
  const int bcol = bx * 256;

  if (tid < 256) drow[tid] = diag[brow + tid];
  else           dcol[tid - 256] = diag[bcol + tid - 256];

  // staging constants (2 x 16B per thread per half-tile; src pre-swizzled)
  const int c0 = tid, c1 = tid + 512;
  const size_t off0 = (size_t)(c0 >> 3) * ND + (size_t)((((c0 & 7) ^ ((c0 >> 3) & 7))) * 8);
  const size_t off1 = (size_t)(c1 >> 3) * ND + (size_t)((((c1 & 7) ^ ((c1 >> 3) & 7))) * 8);
  const int lo0 = tid * 8, lo1 = tid * 8 + 4096;

  const unsigned short* pA0 = f1n + (size_t)brow * ND;
  const unsigned short* pA1 = pA0 + (size_t)128 * ND;
  const unsigned short* pB0 = f2n + (size_t)bcol * ND;
  const unsigned short* pB1 = pB0 + (size_t)128 * ND;

  #define STAGE(ldsbase, g, kk) do { \
    GLOAD_LDS16((g) + off0 + (kk), (ldsbase) + lo0); \
    GLOAD_LDS16((g) + off1 + (kk), (ldsbase) + lo1); } while (0)

  f32x4 acc[8][4];
  #pragma unroll
  for (int m = 0; m < 8; m++)
    #pragma unroll
    for (int n = 0; n < 4; n++)
      acc[m][n] = (f32x4){0.f, 0.f, 0.f, 0.f};

  // fragment read constants (swizzled)
  const int hi = lane >> 4, l15 = lane & 15;
  const int x7 = l15 & 7;
  const int swz0 = (hi ^ x7) * 8;
  const int swz1 = ((hi + 4) ^ x7) * 8;
  const int abase = (wm * 128 + l15) * 64;
  const int bbase = (wn * 64 + l15) * 64;

  // frag register sets (double-buffered aLo and b0; roles swap per tile)
  bf16x8 aL0[4][2], aL1[4][2];
  bf16x8 aH[4][2];
  bf16x8 b0A[2][2], b0B[2][2];
  bf16x8 b1f[2][2];

  #define RD_ALO(dst, P) do { _Pragma("unroll") \
    for (int m = 0; m < 4; ++m) { \
      dst[m][0] = *(const bf16x8*)&(P)[abase + m * 1024 + swz0]; \
      dst[m][1] = *(const bf16x8*)&(P)[abase + m * 1024 + swz1]; } } while (0)
  #define RD_AHI(dst, P) do { _Pragma("unroll") \
    for (int m = 0; m < 4; ++m) { \
      dst[m][0] = *(const bf16x8*)&(P)[abase + (m + 4) * 1024 + swz0]; \
      dst[m][1] = *(const bf16x8*)&(P)[abase + (m + 4) * 1024 + swz1]; } } while (0)
  #define RD_B0(dst, P) do { _Pragma("unroll") \
    for (int n = 0; n < 2; ++n) { \
      dst[n][0] = *(const bf16x8*)&(P)[bbase + n * 1024 + swz0]; \
      dst[n][1] = *(const bf16x8*)&(P)[bbase + n * 1024 + swz1]; } } while (0)
  #define RD_B1(dst, P) do { _Pragma("unroll") \
    for (int n = 0; n < 2; ++n) { \
      dst[n][0] = *(const bf16x8*)&(P)[bbase + (n + 2) * 1024 + swz0]; \
      dst[n][1] = *(const bf16x8*)&(P)[bbase + (n + 2) * 1024 + swz1]; } } while (0)

  #define MFMAQ(MO, NO, A, B) do { \
    __builtin_amdgcn_s_setprio(1); \
    _Pragma("unroll") \
    for (int k = 0; k < 2; ++k) \
      _Pragma("unroll") \
      for (int m = 0; m < 4; ++m) \
        _Pragma("unroll") \
        for (int n = 0; n < 2; ++n) \
          acc[m + MO][n + NO] = __builtin_amdgcn_mfma_f32_16x16x32_bf16( \
              A[m][k], B[n][k], acc[m + MO][n + NO], 0, 0, 0); \
    __builtin_amdgcn_s_setprio(0); } while (0)

  // ---- prologue: tile0 full + B0(1),A0(1) in flight; certify tile0 staged
  // for ALL waves (WAITV then BAR) before any frag read.
  STAGE(&S[0][0][0],    pA0, 0);
  STAGE(&S[0][1][0],    pB0, 0);
  STAGE(&S[0][0][8192], pA1, 0);
  STAGE(&S[0][1][8192], pB1, 0);
  STAGE(&S[1][1][0],    pB0, BK);
  STAGE(&S[1][0][0],    pA0, BK);
  WAITV(4);
  BAR();
  SCHEDB();
  RD_ALO(aL0, (&S[0][0][0]));
  RD_B0(b0A, (&S[0][1][0]));

  #define BODY(BI, NI, CAL, NAL, CB0, NB0, t) do { \
    const int k1 = (((t) + 1) & 15) * BK; \
    const int k2 = (((t) + 2) & 15) * BK; \
    const unsigned short* PA  = &S[BI][0][0]; \
    const unsigned short* PB  = &S[BI][1][0]; \
    const unsigned short* PAn = &S[NI][0][0]; \
    const unsigned short* PBn = &S[NI][1][0]; \
    /* p1: read b1(t) [guaranteed by p3(t-1) WAITV+BAR]; stage B1(t+1); Q00 */ \
    RD_B1(b1f, PB); \
    STAGE(&S[NI][1][8192], pB1, k1); \
    SCHEDB(); \
    BAR(); \
    MFMAQ(0, 0, CAL, CB0); \
    BAR(); \
    /* p2: read aHi(t) [guaranteed by p4(t-1) WAITV+BAR]; stage A1(t+1); Q01 */ \
    RD_AHI(aH, PA); \
    STAGE(&S[NI][0][8192], pA1, k1); \
    SCHEDB(); \
    BAR(); \
    MFMAQ(0, 2, CAL, b1f); \
    BAR(); \
    /* p3: stage B0(t+2); WAITV(4) [own B0,A0,B1(t+1) done]; BAR [ALL waves]; read b0(t+1); Q10 */ \
    STAGE(&S[BI][1][0], pB0, k2); \
    WAITV(4); \
    BAR(); \
    SCHEDB(); \
    RD_B0(NB0, PBn); \
    MFMAQ(4, 0, aH, CB0); \
    BAR(); \
    /* p4: stage A0(t+2); WAITV(4) [own A1(t+1) done]; BAR; read aLo(t+1); Q11 */ \
    STAGE(&S[BI][0][0], pA0, k2); \
    WAITV(4); \
    BAR(); \
    SCHEDB(); \
    RD_ALO(NAL, PAn); \
    MFMAQ(4, 2, aH, b1f); \
    BAR(); } while (0)

  for (int u = 0; u < NT / 2; ++u) {
    BODY(0, 1, aL0, aL1, b0A, b0B, 2 * u);
    BODY(1, 0, aL1, aL0, b0B, b0A, 2 * u + 1);
  }
  #undef BODY

  // ---- epilogue: masked exp accumulation (validated mapping) ----
  const int cgrp = lane >> 4;
  const int c15  = lane & 15;
  float rp[8][4];
  float cp[4];
  #pragma unroll
  for (int m = 0; m < 8; m++)
    #pragma unroll
    for (int r = 0; r < 4; r++) rp[m][r] = 0.f;
  #pragma unroll
  for (int n = 0; n < 4; n++) cp[n] = 0.f;

  #pragma unroll
  for (int n = 0; n < 4; n++) {
    const int ct   = wn * 64 + n * 16 + c15;
    const int gcol = bcol + ct;
    const float dc = dcol[ct];
    #pragma unroll
    for (int m = 0; m < 8; m++) {
      #pragma unroll
      for (int r = 0; r < 4; r++) {
        const int rt   = wm * 128 + m * 16 + cgrp * 4 + r;
        const int grow = brow + rt;
        const float s  = acc[m][n][r];
        const float e  = __expf(BETA * (s - BASE));
        const float dr = drow[rt];
        const bool off = (grow != gcol);
        if (off && (s + MARGIN > dr)) rp[m][r] += e;
        if (off && (s + MARGIN > dc)) cp[n] += e;
      }
    }
  }
  #pragma unroll
  for (int m = 0; m < 8; m++) {
    #pragma unroll
    for (int r = 0; r < 4; r++) {
      float v = rp[m][r];
      v += __shfl_xor(v, 1); v += __shfl_xor(v, 2);
      v += __shfl_xor(v, 4); v += __shfl_xor(v, 8);
      if (c15 == 0) {
        const int rt = wm * 128 + m * 16 + cgrp * 4 + r;
        atomicAdd(&row_sum[brow + rt], v);
      }
    }
  }
  #pragma unroll
  for (int n = 0; n < 4; n++) {
    float v = cp[n];
    v += __shfl_xor(v, 16); v += __shfl_xor(v, 32);
    if (cgrp == 0) {
      const int ct = wn * 64 + n * 16 + c15;
      atomicAdd(&col_sum[bcol + ct], v);
    }
  }
  #undef STAGE
}

// --------------------------------------------------------------------------
// K3: final scalar reduction
__global__ __launch_bounds__(1024) void finalize_kernel(
    const float* __restrict__ diag, const float* __restrict__ row_sum,
    const float* __restrict__ col_sum, float* __restrict__ out)
{
  const int tid = threadIdx.x;
  float sp = 0.f, sr = 0.f, sc = 0.f;
  for (int i = tid; i < NB; i += 1024) {
    const float pos = diag[i];
    const float x = -ALPHA * (pos - BASE);
    sp += (fmaxf(x, 0.f) + log1pf(__expf(-fabsf(x)))) / ALPHA;
    sr += log1pf(row_sum[i]);
    sc += log1pf(col_sum[i]);
  }
  #pragma unroll
  for (int m = 1; m < 64; m <<= 1) {
    sp += __shfl_xor(sp, m);
    sr += __shfl_xor(sr, m);
    sc += __shfl_xor(sc, m);
  }
  __shared__ float red[3][16];
  const int wid = tid >> 6, lane = tid & 63;
  if (lane == 0) { red[0][wid] = sp; red[1][wid] = sr; red[2][wid] = sc; }
  __syncthreads();
  if (tid == 0) {
    sp = 0.f; sr = 0.f; sc = 0.f;
    #pragma unroll
    for (int w = 0; w < 16; w++) { sp += red[0][w]; sr += red[1][w]; sc += red[2][w]; }
    out[0] = sp / (float)NB + (sr + sc) / (2.f * BETA * (float)NB);
  }
}

// --------------------------------------------------------------------------
extern "C" void kernel_launch(void* const* d_in, const int* in_sizes, int n_in,
                              void* d_out, int out_size, void* d_ws, size_t ws_size,
                              hipStream_t stream) {
  const float* f1 = (const float*)d_in[0];
  const float* f2 = (const float*)d_in[1];
  float* out = (float*)d_out;

  char* ws = (char*)d_ws;
  unsigned short* f1n = (unsigned short*)ws;                               // 16 MB
  unsigned short* f2n = (unsigned short*)(ws + (size_t)16 * 1024 * 1024);  // 16 MB
  float* diag    = (float*)(ws + (size_t)32 * 1024 * 1024);                // 32 KB
  float* row_sum = diag + NB;                                              // 32 KB
  float* col_sum = row_sum + NB;                                           // 32 KB

  norm_diag_kernel<<<NB, 256, 0, stream>>>(f1, f2, f1n, f2n, diag, row_sum, col_sum);

  dim3 grid(NB / 256, NB / 256);
  simloss_gemm_kernel<<<grid, 512, 0, stream>>>(f1n, f2n, diag, row_sum, col_sum);

  finalize_kernel<<<1, 1024, 0, stream>>>(diag, row_sum, col_sum, out);
}